// Round 5
// baseline (436.440 us; speedup 1.0000x reference)
//
#include <hip/hip_runtime.h>

#define NB 16
#define NC 64
#define C2 32
#define C4 16
#define HH 256
#define WW 256
#define HW (HH*WW)          // 65536

// ws layout (floats):
//   [0, 2048)        w1T   : w1T[c*32+o] = w1[o*64+c]
//   [2048, 10240)    S1    : [b][o32][s16]   (per-b stride 512)
//   [10240, 18432)   S2
//   [18432, 26624)   S3
//   [26624, 30720)   gates : [b][o16][s16]   (per-b stride 256)

__global__ __launch_bounds__(256) void prep_kernel(const float* __restrict__ w1,
                                                   float* __restrict__ ws) {
    int t = threadIdx.x;
    for (int i = t; i < 24576; i += 256) ws[2048 + i] = 0.f;
    for (int i = t; i < 2048; i += 256) {
        int o = i >> 6, c = i & 63;
        ws[c * 32 + o] = w1[i];
    }
}

// Stats: S1,S2,S3 per (b, o in [0,32), s in [0,16)) over the 4096 spatial blocks.
// Block = (b, r=h%4, chunk). Thread = column; owns 4 rows (all h%4==r -> fixed s).
// 4 blocks/CU * 4 waves = 4 waves/SIMD (VGPR capped at 128 by launch_bounds).
__global__ __launch_bounds__(256, 4) void stats_kernel(const float* __restrict__ x,
                                                       const float* __restrict__ w1t,
                                                       const float* __restrict__ b1,
                                                       float* __restrict__ stats) {
    int b     = blockIdx.x >> 6;   // 64 blocks per batch
    int sub   = blockIdx.x & 63;
    int r     = sub >> 4;          // h residue 0..3
    int chunk = sub & 15;          // 16 row-chunks
    int t     = threadIdx.x;       // column w
    int lane  = t & 63;
    int wid   = t >> 6;
    const float* xb = x + (size_t)b * NC * HW + t;

    float S1[32], S2[32], S3[32];
    #pragma unroll
    for (int o = 0; o < 32; o++) { S1[o] = 0.f; S2[o] = 0.f; S3[o] = 0.f; }

    #pragma unroll 1
    for (int p = 0; p < 4; ++p) {
        int h = r + 4 * (chunk * 4 + p);
        const float* xp = xb + (size_t)h * WW;

        float xr[64];
        #pragma unroll
        for (int c = 0; c < 64; c++) xr[c] = xp[(size_t)c * HW];
        __builtin_amdgcn_sched_barrier(0);   // keep loads ahead of the conv

        float acc[32];
        #pragma unroll
        for (int o = 0; o < 32; o++) acc[o] = b1[o];
        #pragma unroll
        for (int c = 0; c < 64; c++) {
            float xc = xr[c];
            #pragma unroll
            for (int o = 0; o < 32; o++) acc[o] += w1t[c * 32 + o] * xc;
        }
        #pragma unroll
        for (int o = 0; o < 32; o++) {
            float v = fmaxf(acc[o], 0.f);
            float pw = v * v;
            S1[o] += v;
            S2[o] += pw;
            S3[o] += pw * v;
        }
    }

    // Butterfly-reduce over the 16 lanes sharing (lane & 3), then combine the
    // 4 waves through LDS; one atomicAdd per (o, s4, stat) per block.
    __shared__ float red[3][4][128];
    #pragma unroll
    for (int o = 0; o < 32; o++) {
        float a = S1[o], bb = S2[o], cc = S3[o];
        #pragma unroll
        for (int m = 4; m <= 32; m <<= 1) {
            a  += __shfl_xor(a,  m);
            bb += __shfl_xor(bb, m);
            cc += __shfl_xor(cc, m);
        }
        if (lane < 4) {
            red[0][wid][o * 4 + lane] = a;
            red[1][wid][o * 4 + lane] = bb;
            red[2][wid][o * 4 + lane] = cc;
        }
    }
    __syncthreads();
    if (t < 128) {
        int o = t >> 2, s4 = t & 3;
        int idx = b * 512 + o * 16 + r * 4 + s4;
        #pragma unroll
        for (int st = 0; st < 3; st++) {
            float v = red[st][0][t] + red[st][1][t] + red[st][2][t] + red[st][3][t];
            atomicAdd(&stats[st * 8192 + idx], v);
        }
    }
}

// Tiny attention: qkv = mean + m3; softmax(q q^T) @ v; gate = sigmoid(y).
__global__ __launch_bounds__(512) void attn_kernel(const float* __restrict__ stats,
                                                   float* __restrict__ gates) {
    int b = blockIdx.x;
    int t = threadIdx.x;
    __shared__ float qkv[512];
    {
        int idx = b * 512 + t;
        float S1 = stats[idx];
        float S2 = stats[8192 + idx];
        float S3 = stats[16384 + idx];
        float mu = S1 * (1.f / 4096.f);
        float m3 = (S3 - 3.f * mu * S2 + 2.f * 4096.f * mu * mu * mu) * (1.f / 16.f);
        qkv[t] = mu + m3;
    }
    __syncthreads();
    if (t < 256) {
        int o = t >> 4, s = t & 15;
        float qs = qkv[o * 16 + s];
        float mx = -1e30f;
        #pragma unroll
        for (int k = 0; k < 16; k++) mx = fmaxf(mx, qs * qkv[o * 16 + k]);
        float sum = 0.f, y = 0.f;
        #pragma unroll
        for (int k = 0; k < 16; k++) {
            float e = __expf(qs * qkv[o * 16 + k] - mx);
            sum += e;
            y   += e * qkv[(16 + o) * 16 + k];
        }
        y /= sum;
        float g = 1.f / (1.f + __expf(-y));
        gates[b * 256 + o * 16 + s] = g;
    }
}

// Per-pixel: recompute vx channels, gate, 16->64 conv, + bias + residual.
__global__ __launch_bounds__(256) void out_kernel(const float* __restrict__ x,
                                                  const float* __restrict__ w1t,
                                                  const float* __restrict__ b1,
                                                  const float* __restrict__ w2,
                                                  const float* __restrict__ b2,
                                                  const float* __restrict__ gates,
                                                  float* __restrict__ out) {
    int bh = blockIdx.x;
    int b  = bh >> 8;      // 256 rows per batch
    int h  = bh & 255;
    int w  = threadIdx.x;  // 0..255
    int s  = (h & 3) * 4 + (w & 3);
    const float* xb = x   + (size_t)b * NC * HW + h * WW + w;
    float*       ob = out + (size_t)b * NC * HW + h * WW + w;

    __shared__ float gsh[256];
    gsh[w] = gates[b * 256 + w];
    __syncthreads();

    float xr[64];
    #pragma unroll
    for (int c = 0; c < 64; c++) xr[c] = xb[(size_t)c * HW];

    float fv[16];
    #pragma unroll
    for (int j = 0; j < 16; j++) fv[j] = b1[16 + j];
    #pragma unroll
    for (int c = 0; c < 64; c++) {
        float xc = xr[c];
        #pragma unroll
        for (int j = 0; j < 16; j++) fv[j] += w1t[c * 32 + 16 + j] * xc;
    }
    #pragma unroll
    for (int j = 0; j < 16; j++) {
        float v = fv[j] > 0.f ? fv[j] : 0.f;
        fv[j] = v * gsh[j * 16 + s];
    }
    #pragma unroll
    for (int o = 0; o < 64; o++) {
        float r = b2[o] + xr[o];
        #pragma unroll
        for (int j = 0; j < 16; j++) r += w2[o * 16 + j] * fv[j];
        ob[(size_t)o * HW] = r;
    }
}

extern "C" void kernel_launch(void* const* d_in, const int* in_sizes, int n_in,
                              void* d_out, int out_size, void* d_ws, size_t ws_size,
                              hipStream_t stream) {
    const float* x  = (const float*)d_in[0];
    const float* w1 = (const float*)d_in[1];
    const float* b1 = (const float*)d_in[2];
    const float* w2 = (const float*)d_in[3];
    const float* b2 = (const float*)d_in[4];
    float* ws    = (float*)d_ws;
    float* w1t   = ws;
    float* stats = ws + 2048;
    float* gates = ws + 26624;
    float* out   = (float*)d_out;

    prep_kernel <<<1,    256, 0, stream>>>(w1, ws);
    stats_kernel<<<1024, 256, 0, stream>>>(x, w1t, b1, stats);
    attn_kernel <<<16,   512, 0, stream>>>(stats, gates);
    out_kernel  <<<4096, 256, 0, stream>>>(x, w1t, b1, w2, b2, gates, out);
}

// Round 6
// 231.665 us; speedup vs baseline: 1.8839x; 1.8839x over previous
//
#include <hip/hip_runtime.h>

#define NB 16
#define NC 64
#define C2 32
#define C4 16
#define HH 256
#define WW 256
#define HW (HH*WW)          // 65536

// ws layout (floats):
//   [0, 2048)        w1T   : w1T[c*32+o] = w1[o*64+c]
//   [2048, 10240)    S1    : [b][o32][s16]   (per-b stride 512)
//   [10240, 18432)   S2
//   [18432, 26624)   S3
//   [26624, 30720)   gates : [b][o16][s16]   (per-b stride 256)

__global__ __launch_bounds__(256) void prep_kernel(const float* __restrict__ w1,
                                                   float* __restrict__ ws) {
    int t = threadIdx.x;
    for (int i = t; i < 24576; i += 256) ws[2048 + i] = 0.f;
    for (int i = t; i < 2048; i += 256) {
        int o = i >> 6, c = i & 63;
        ws[c * 32 + o] = w1[i];
    }
}

__device__ __forceinline__ void gl_lds16(const float* g, float* l) {
    __builtin_amdgcn_global_load_lds(
        (const __attribute__((address_space(1))) unsigned int*)g,
        (__attribute__((address_space(3))) unsigned int*)l,
        16, 0, 0);
}

// Stats: S1,S2,S3 per (b, o in [0,32), s in [0,16)).
// Block = (b, r=h%4, 8-row chunk, 64-col segment). Waves split o (8 each) so
// per-thread persistent state is tiny; x shared via 16KB double-buffered LDS
// stages filled with global_load_lds; counted vmcnt keeps loads in flight.
__global__ __launch_bounds__(256) void stats_kernel(const float* __restrict__ x,
                                                    const float* __restrict__ w1t,
                                                    const float* __restrict__ b1,
                                                    float* __restrict__ stats) {
    __shared__ float sbuf[2][64 * 64];   // 2 x 16KB

    int bid   = blockIdx.x;
    int b     = bid >> 7;          // 128 blocks per batch
    int rest  = bid & 127;
    int r     = rest >> 5;         // h residue 0..3
    int rest2 = rest & 31;
    int chunk = rest2 >> 2;        // 8 row-chunks (8 rows each)
    int colc  = rest2 & 3;         // 4 column segments of 64
    int t     = threadIdx.x;
    int lane  = t & 63;            // column within segment
    int wid   = t >> 6;            // wave id = o-group
    int ogs   = __builtin_amdgcn_readfirstlane(wid);

    const float* xseg = x + (size_t)b * NC * HW + colc * 64;
    const float* wt   = w1t + ogs * 8;        // uniform -> s_load path
    float bias[8];
    #pragma unroll
    for (int o = 0; o < 8; o++) bias[o] = b1[ogs * 8 + o];

    // Stage row p into sbuf[p&1]: wave wid stages channels wid*16 .. wid*16+15.
    // One wave-load covers 4 channel-rows (lane L -> ch c0+(L>>4), col (L&15)*4).
#define STAGE(p_) do {                                                         \
        int h_ = r + 4 * (chunk * 8 + (p_));                                   \
        const float* gs_ = xseg + (size_t)h_ * WW;                             \
        float* ls_ = &sbuf[(p_) & 1][0];                                       \
        _Pragma("unroll")                                                      \
        for (int k_ = 0; k_ < 4; ++k_) {                                       \
            int c0_ = wid * 16 + k_ * 4;                                       \
            gl_lds16(gs_ + (size_t)(c0_ + (lane >> 4)) * HW + (lane & 15) * 4, \
                     ls_ + c0_ * 64);                                          \
        }                                                                      \
    } while (0)

    float S1[8], S2[8], S3[8];
    #pragma unroll
    for (int o = 0; o < 8; o++) { S1[o] = 0.f; S2[o] = 0.f; S3[o] = 0.f; }

    STAGE(0);
    #pragma unroll 1
    for (int p = 0; p < 8; ++p) {
        if (p < 7) {
            STAGE(p + 1);
            asm volatile("s_waitcnt vmcnt(4)" ::: "memory");   // stage p landed
        } else {
            asm volatile("s_waitcnt vmcnt(0)" ::: "memory");
        }
        __builtin_amdgcn_s_barrier();

        const float* L = &sbuf[p & 1][0];
        float acc[8];
        #pragma unroll
        for (int o = 0; o < 8; o++) acc[o] = bias[o];
        #pragma unroll
        for (int c = 0; c < 64; ++c) {
            float xc = L[c * 64 + lane];
            #pragma unroll
            for (int o = 0; o < 8; o++) acc[o] += wt[c * 32 + o] * xc;
        }
        #pragma unroll
        for (int o = 0; o < 8; o++) {
            float v = fmaxf(acc[o], 0.f);
            float pw = v * v;
            S1[o] += v;
            S2[o] += pw;
            S3[o] += pw * v;
        }
        __builtin_amdgcn_s_barrier();   // reads of sbuf[p&1] done before restage
    }
#undef STAGE

    // Sum over the 16 lanes sharing (lane & 3); lanes 0..3 hold s4 = lane.
    #pragma unroll
    for (int o = 0; o < 8; o++) {
        float a = S1[o], bb = S2[o], cc = S3[o];
        #pragma unroll
        for (int m = 4; m <= 32; m <<= 1) {
            a  += __shfl_xor(a,  m);
            bb += __shfl_xor(bb, m);
            cc += __shfl_xor(cc, m);
        }
        if (lane < 4) {
            int idx = b * 512 + (ogs * 8 + o) * 16 + r * 4 + lane;
            atomicAdd(&stats[idx],         a);
            atomicAdd(&stats[8192 + idx],  bb);
            atomicAdd(&stats[16384 + idx], cc);
        }
    }
}

// Tiny attention: qkv = mean + m3; softmax(q q^T) @ v; gate = sigmoid(y).
__global__ __launch_bounds__(512) void attn_kernel(const float* __restrict__ stats,
                                                   float* __restrict__ gates) {
    int b = blockIdx.x;
    int t = threadIdx.x;
    __shared__ float qkv[512];
    {
        int idx = b * 512 + t;
        float S1 = stats[idx];
        float S2 = stats[8192 + idx];
        float S3 = stats[16384 + idx];
        float mu = S1 * (1.f / 4096.f);
        float m3 = (S3 - 3.f * mu * S2 + 2.f * 4096.f * mu * mu * mu) * (1.f / 16.f);
        qkv[t] = mu + m3;
    }
    __syncthreads();
    if (t < 256) {
        int o = t >> 4, s = t & 15;
        float qs = qkv[o * 16 + s];
        float mx = -1e30f;
        #pragma unroll
        for (int k = 0; k < 16; k++) mx = fmaxf(mx, qs * qkv[o * 16 + k]);
        float sum = 0.f, y = 0.f;
        #pragma unroll
        for (int k = 0; k < 16; k++) {
            float e = __expf(qs * qkv[o * 16 + k] - mx);
            sum += e;
            y   += e * qkv[(16 + o) * 16 + k];
        }
        y /= sum;
        float g = 1.f / (1.f + __expf(-y));
        gates[b * 256 + o * 16 + s] = g;
    }
}

// Per-pixel: recompute vx channels, gate, 16->64 conv, + bias + residual.
__global__ __launch_bounds__(256) void out_kernel(const float* __restrict__ x,
                                                  const float* __restrict__ w1t,
                                                  const float* __restrict__ b1,
                                                  const float* __restrict__ w2,
                                                  const float* __restrict__ b2,
                                                  const float* __restrict__ gates,
                                                  float* __restrict__ out) {
    int bh = blockIdx.x;
    int b  = bh >> 8;      // 256 rows per batch
    int h  = bh & 255;
    int w  = threadIdx.x;  // 0..255
    int s  = (h & 3) * 4 + (w & 3);
    const float* xb = x   + (size_t)b * NC * HW + h * WW + w;
    float*       ob = out + (size_t)b * NC * HW + h * WW + w;

    __shared__ float gsh[256];
    gsh[w] = gates[b * 256 + w];
    __syncthreads();

    float xr[64];
    #pragma unroll
    for (int c = 0; c < 64; c++) xr[c] = xb[(size_t)c * HW];

    float fv[16];
    #pragma unroll
    for (int j = 0; j < 16; j++) fv[j] = b1[16 + j];
    #pragma unroll
    for (int c = 0; c < 64; c++) {
        float xc = xr[c];
        #pragma unroll
        for (int j = 0; j < 16; j++) fv[j] += w1t[c * 32 + 16 + j] * xc;
    }
    #pragma unroll
    for (int j = 0; j < 16; j++) {
        float v = fv[j] > 0.f ? fv[j] : 0.f;
        fv[j] = v * gsh[j * 16 + s];
    }
    #pragma unroll
    for (int o = 0; o < 64; o++) {
        float r = b2[o] + xr[o];
        #pragma unroll
        for (int j = 0; j < 16; j++) r += w2[o * 16 + j] * fv[j];
        ob[(size_t)o * HW] = r;
    }
}

extern "C" void kernel_launch(void* const* d_in, const int* in_sizes, int n_in,
                              void* d_out, int out_size, void* d_ws, size_t ws_size,
                              hipStream_t stream) {
    const float* x  = (const float*)d_in[0];
    const float* w1 = (const float*)d_in[1];
    const float* b1 = (const float*)d_in[2];
    const float* w2 = (const float*)d_in[3];
    const float* b2 = (const float*)d_in[4];
    float* ws    = (float*)d_ws;
    float* w1t   = ws;
    float* stats = ws + 2048;
    float* gates = ws + 26624;
    float* out   = (float*)d_out;

    prep_kernel <<<1,    256, 0, stream>>>(w1, ws);
    stats_kernel<<<2048, 256, 0, stream>>>(x, w1t, b1, stats);
    attn_kernel <<<16,   512, 0, stream>>>(stats, gates);
    out_kernel  <<<4096, 256, 0, stream>>>(x, w1t, b1, w2, b2, gates, out);
}